// Round 6
// baseline (106.322 us; speedup 1.0000x reference)
//
#include <hip/hip_runtime.h>

// RelationalDense: out[n,:] = feat[n,:] @ W[rel[n]] + bias,  W = einsum('rb,bfo', lin, V)
// N=65536, F=64, U=64, R=25, B=8.
//
// Buckets rows by relation so every wave is relation-uniform.
// R6: inverted compute layout. R4/R5's inner loop streamed W via 64 uniform
// loads per wave (s_load storm / lgkmcnt stalls) and stored 64-scattered-line
// writes; feature-load staging (R5) proved loads weren't the bottleneck.
// Now: lane j keeps W[:,j] in 64 VGPRs (loaded ONCE, coalesced, L1-reused by
// the 64 blocks per relation); features LDS-broadcast per row; per row the
// wave does 16 ds_read_b128 (same-addr broadcast) + 64 v_fmac (4 chains) +
// ONE coalesced 256B store. Wave-uniform trip count skips empty bucket tail.

typedef float v4f __attribute__((ext_vector_type(4)));

#define NN 65536
#define FF 64
#define UU 64
#define RR 25
#define BB 8
#define CAP 4096                 // slots per bucket; mean fill 2621, +29 sigma safe
#define NSLOT (RR * CAP)         // 102400

// ws layout:
//   [0, NSLOT*4)           idx_sorted (int)  -- NOT memset; validity = pos < cnt
//   [NSLOT*4, +128)        cursors (25 ints), memset 0; == bucket counts after k_prep
//   [W_OFF, +R*F*U*4)      W fp32
#define IDX_OFF 0
#define CUR_OFF (NSLOT * 4)
#define W_OFF   (NSLOT * 4 + 128)
#define WS_NEED ((size_t)(W_OFF + RR * FF * UU * 4))

// ---------------------------------------------------------------------------
// K1: fused W precompute (blocks [0,400)) + bucket scatter (blocks [400,656))
// ---------------------------------------------------------------------------
__global__ __launch_bounds__(256) void k_prep(
    const float* __restrict__ kern,   // [B,F,U]
    const float* __restrict__ lin,    // [R,B]
    const int*   __restrict__ rel,    // [N]
    float*       __restrict__ W,      // [R,F,U]
    int*         __restrict__ idx_sorted,
    int*         __restrict__ cursors) {
  const int wblocks = (RR * FF * UU) / 256;  // 400
  int bid = blockIdx.x;
  if (bid < wblocks) {
    int idx = bid * 256 + threadIdx.x;
    int r  = __builtin_amdgcn_readfirstlane(idx >> 12);
    int fo = idx & (FF * UU - 1);
    float acc = 0.f;
#pragma unroll
    for (int b = 0; b < BB; ++b)
      acc += lin[r * BB + b] * kern[b * (FF * UU) + fo];
    W[idx] = acc;
  } else {
    // scatter: block of 256 rows -> LDS histogram -> reserve global range -> place
    int sb  = bid - wblocks;
    int tid = threadIdx.x;
    __shared__ int cnt[RR], base[RR], lcur[RR];
    if (tid < RR) { cnt[tid] = 0; lcur[tid] = 0; }
    __syncthreads();
    int row = sb * 256 + tid;
    int r = rel[row];
    atomicAdd(&cnt[r], 1);
    __syncthreads();
    if (tid < RR) base[tid] = atomicAdd(&cursors[tid], cnt[tid]);
    __syncthreads();
    int loc = atomicAdd(&lcur[r], 1);
    idx_sorted[r * CAP + base[r] + loc] = row;
  }
}

// ---------------------------------------------------------------------------
// K2: main compute, inverted layout. Block 256 = 4 waves; block owns 64 slots.
// Lane j holds W_r[:,j] in 64 VGPRs. Wave w processes local rows
// [16w, 16w+vw): per row 16 LDS broadcasts + 64 fmac + 1 coalesced store.
// ---------------------------------------------------------------------------
__global__ __launch_bounds__(256, 4) void k_main(
    const float* __restrict__ features,  // [N,F]
    const float* __restrict__ bias,      // [U]
    const float* __restrict__ W,         // [R,F,U]
    const int*   __restrict__ idx_sorted,
    const int*   __restrict__ cursors,   // bucket counts after k_prep
    float*       __restrict__ out) {     // [N,U]
  __shared__ int srow[64];
  __shared__ v4f sfeat[64][17];          // 17408 B; pad breaks 256B-stride banks

  int tid       = threadIdx.x;
  int base_slot = blockIdx.x * 64;
  int r   = __builtin_amdgcn_readfirstlane(base_slot >> 12);  // uniform (CAP%64==0)
  int cnt = cursors[r];                                       // uniform -> s_load
  int bpos  = base_slot & (CAP - 1);
  int valid = cnt - bpos;                // block-uniform # of valid local rows
  if (valid <= 0) return;                // whole block in empty tail (uniform exit)
  if (valid > 64) valid = 64;

  if (tid < 64)
    srow[tid] = (tid < valid) ? idx_sorted[base_slot + tid] : -1;
  __syncthreads();

  // ---- stage features: 4 lanes per row -> 16 lines/instr, loaded once ----
  const v4f* f4 = reinterpret_cast<const v4f*>(features);
#pragma unroll
  for (int i = 0; i < 4; ++i) {
    int s   = i * 256 + tid;
    int rl  = s >> 4;                    // local row 0..63
    int seg = s & 15;
    if (rl < valid)
      sfeat[rl][seg] = f4[(size_t)srow[rl] * 16 + seg];
  }

  // ---- lane j owns W column j: 64 coalesced dword loads, L1-reused ----
  int j = tid & 63;
  const float* Wr = W + r * (FF * UU);   // uniform base
  float wcol[64];
#pragma unroll
  for (int f = 0; f < FF; ++f)
    wcol[f] = Wr[f * UU + j];            // 256B coalesced per instr
  float bj = bias[j];
  __syncthreads();

  int wu = __builtin_amdgcn_readfirstlane(tid >> 6);  // wave id 0..3
  int vw = valid - wu * 16;              // wave-uniform rows for this wave
  if (vw > 16) vw = 16;

  for (int rl = 0; rl < vw; ++rl) {      // dynamic, uniform trip count
    int lrow = wu * 16 + rl;
    float a0 = bj, a1 = 0.f, a2 = 0.f, a3 = 0.f;   // 4 chains hide fmac latency
#pragma unroll
    for (int k = 0; k < 16; ++k) {
      v4f fv = sfeat[lrow][k];           // ds_read_b128, same-addr broadcast
      a0 += fv[0] * wcol[4 * k + 0];
      a1 += fv[1] * wcol[4 * k + 1];
      a2 += fv[2] * wcol[4 * k + 2];
      a3 += fv[3] * wcol[4 * k + 3];
    }
    float o = (a0 + a1) + (a2 + a3);
    int row = __builtin_amdgcn_readfirstlane(srow[lrow]);  // uniform -> saddr
    out[(size_t)row * UU + j] = o;       // 256B contiguous store (4 lines)
  }
}

// ---------------------------------------------------------------------------
// Fallback (no workspace): compute W_r on the fly per row. Safety net only.
// ---------------------------------------------------------------------------
__global__ __launch_bounds__(256) void k_fallback(
    const float* __restrict__ features,
    const int*   __restrict__ rel,
    const float* __restrict__ kern,
    const float* __restrict__ lin,
    const float* __restrict__ bias,
    float*       __restrict__ out) {
  int tid = threadIdx.x;
  int row = blockIdx.x * 64 + (tid & 63);
  int q   = __builtin_amdgcn_readfirstlane(tid >> 6);
  int r   = rel[row];
  float cf[BB];
#pragma unroll
  for (int b = 0; b < BB; ++b) cf[b] = lin[r * BB + b];
  const v4f* fr = reinterpret_cast<const v4f*>(features + (size_t)row * FF);
  float acc[16];
#pragma unroll
  for (int j = 0; j < 16; ++j) acc[j] = bias[q * 16 + j];
#pragma unroll
  for (int ch = 0; ch < 4; ++ch) {
    v4f fv[4];
#pragma unroll
    for (int k = 0; k < 4; ++k) fv[k] = fr[ch * 4 + k];
#pragma unroll
    for (int k = 0; k < 4; ++k) {
#pragma unroll
      for (int c = 0; c < 4; ++c) {
        int f = ch * 16 + k * 4 + c;
        float fs = fv[k][c];
        float wf[16];
#pragma unroll
        for (int jj = 0; jj < 16; ++jj) wf[jj] = 0.f;
#pragma unroll
        for (int b = 0; b < BB; ++b) {
          const float* Vb = kern + b * (FF * UU) + f * UU + q * 16;
#pragma unroll
          for (int jj = 0; jj < 16; ++jj) wf[jj] += cf[b] * Vb[jj];
        }
#pragma unroll
        for (int jj = 0; jj < 16; ++jj) acc[jj] += fs * wf[jj];
      }
    }
  }
  v4f* o4 = reinterpret_cast<v4f*>(out + (size_t)row * UU + q * 16);
#pragma unroll
  for (int j4 = 0; j4 < 4; ++j4) {
    v4f v = {acc[4 * j4], acc[4 * j4 + 1], acc[4 * j4 + 2], acc[4 * j4 + 3]};
    o4[j4] = v;
  }
}

extern "C" void kernel_launch(void* const* d_in, const int* in_sizes, int n_in,
                              void* d_out, int out_size, void* d_ws, size_t ws_size,
                              hipStream_t stream) {
  const float* features  = (const float*)d_in[0];
  const int*   relations = (const int*)d_in[1];
  const float* kern      = (const float*)d_in[2];
  const float* lin       = (const float*)d_in[3];
  const float* bias      = (const float*)d_in[4];
  float* out = (float*)d_out;

  if (ws_size >= WS_NEED) {
    char*  ws         = (char*)d_ws;
    int*   idx_sorted = (int*)(ws + IDX_OFF);
    int*   cursors    = (int*)(ws + CUR_OFF);
    float* W          = (float*)(ws + W_OFF);
    (void)hipMemsetAsync(cursors, 0, RR * sizeof(int), stream);   // 100 B only
    k_prep<<<(RR * FF * UU) / 256 + NN / 256, 256, 0, stream>>>(
        kern, lin, relations, W, idx_sorted, cursors);
    k_main<<<NSLOT / 64, 256, 0, stream>>>(features, bias, W, idx_sorted, cursors, out);
  } else {
    k_fallback<<<NN / 64, 256, 0, stream>>>(features, relations, kern, lin, bias, out);
  }
}

// Round 7
// 87.216 us; speedup vs baseline: 1.2191x; 1.2191x over previous
//
#include <hip/hip_runtime.h>

// RelationalDense: out[n,:] = feat[n,:] @ W[rel[n]] + bias,  W = einsum('rb,bfo', lin, V)
// N=65536, F=64, U=64, R=25, B=8.
//
// Buckets rows by relation (wave-uniform W) as before. R7: the fp32 VALU path
// has a hard ~5.3 us fmac-issue floor and measured 22+ us with W-operand
// stalls; R6's W-in-registers hit the unified-file cap (64 VGPR + AGPR spill,
// 138 us). This is 25 bucketed GEMMs [cnt_r x 64]@[64x64] -> use bf16 MFMA
// (harness threshold 0.136 is explicitly bf16-budgeted). k_prep emits W^T as
// bf16; k_main stages feat(bf16) + Wt in LDS, 8 mfma_16x16x32_bf16 per wave,
// bias seeded via C-layout, coalesced 16-lane stores. Compute cost ~0.26 us
// of matrix pipe; kernel becomes pure data movement (~5.4 us HBM floor).

typedef float v4f __attribute__((ext_vector_type(4)));
typedef short bf16x8 __attribute__((ext_vector_type(8)));
typedef float f32x4 __attribute__((ext_vector_type(4)));
typedef unsigned short u16;
typedef u16 u16x4 __attribute__((ext_vector_type(4)));

#define NN 65536
#define FF 64
#define UU 64
#define RR 25
#define BB 8
#define CAP 4096                 // slots per bucket; mean fill 2621, +29 sigma safe
#define NSLOT (RR * CAP)         // 102400
#define SAS 72                   // LDS row stride in bf16 units (144 B, 16B-aligned)

// ws layout:
//   [0, NSLOT*4)           idx_sorted (int)  -- validity = pos < cnt (no memset)
//   [NSLOT*4, +128)        cursors (25 ints), memset 0; == bucket counts after k_prep
//   [WT_OFF, +R*U*F*2)     Wt bf16, transposed [R][U][F]
#define IDX_OFF 0
#define CUR_OFF (NSLOT * 4)
#define WT_OFF  (NSLOT * 4 + 128)
#define WS_NEED ((size_t)(WT_OFF + RR * FF * UU * 2))

__device__ __forceinline__ u16 f2bf(float x) {
  union { float f; unsigned u; } v; v.f = x;
  unsigned r = v.u + 0x7FFF + ((v.u >> 16) & 1);   // round-to-nearest-even
  return (u16)(r >> 16);
}

// ---------------------------------------------------------------------------
// K1: fused W^T precompute (blocks [0,400)) + bucket scatter ([400,656))
// ---------------------------------------------------------------------------
__global__ __launch_bounds__(256) void k_prep(
    const float* __restrict__ kern,   // [B,F,U]
    const float* __restrict__ lin,    // [R,B]
    const int*   __restrict__ rel,    // [N]
    u16*         __restrict__ Wt,     // [R,U,F] bf16
    int*         __restrict__ idx_sorted,
    int*         __restrict__ cursors) {
  const int wblocks = (RR * FF * UU) / 256;  // 400
  int bid = blockIdx.x;
  if (bid < wblocks) {
    int idx = bid * 256 + threadIdx.x;
    int r = __builtin_amdgcn_readfirstlane(idx >> 12);
    int f = (idx >> 6) & 63;
    int u = idx & 63;
    float acc = 0.f;
#pragma unroll
    for (int b = 0; b < BB; ++b)
      acc += lin[r * BB + b] * kern[b * (FF * UU) + f * UU + u];  // coalesced in u
    Wt[r * (FF * UU) + u * FF + f] = f2bf(acc);  // transposed write (tiny, 200 KB)
  } else {
    // scatter: block of 256 rows -> LDS histogram -> reserve global range -> place
    int sb  = bid - wblocks;
    int tid = threadIdx.x;
    __shared__ int cnt[RR], base[RR], lcur[RR];
    if (tid < RR) { cnt[tid] = 0; lcur[tid] = 0; }
    __syncthreads();
    int row = sb * 256 + tid;
    int r = rel[row];
    atomicAdd(&cnt[r], 1);
    __syncthreads();
    if (tid < RR) base[tid] = atomicAdd(&cursors[tid], cnt[tid]);
    __syncthreads();
    int loc = atomicAdd(&lcur[r], 1);
    idx_sorted[r * CAP + base[r] + loc] = row;
  }
}

// ---------------------------------------------------------------------------
// K2: MFMA compute. Block 256 = 4 waves, 64 rows. Wave w computes the 64x16
// output column-tile [16w,16w+16): 4 row-tiles x 2 K-chunks of
// mfma_f32_16x16x32_bf16. Layouts (guide 3, m89/m120 verified):
//   A: m=lane&15 (row), k=quad*8+j     -> sA[row][k] contiguous 16B
//   B: n=lane&15 (col), k=quad*8+j     -> sB[u][f]  contiguous 16B (W^T)
//   C: col=lane&15, row=quad*4+reg     -> bias seeds acc; 16-lane row stores
// ---------------------------------------------------------------------------
__global__ __launch_bounds__(256, 2) void k_main(
    const float* __restrict__ features,  // [N,F] fp32
    const float* __restrict__ bias,      // [U]
    const u16*   __restrict__ Wt,        // [R,U,F] bf16
    const int*   __restrict__ idx_sorted,
    const int*   __restrict__ cursors,
    float*       __restrict__ out) {     // [N,U]
  __shared__ int srow[64];
  __shared__ u16 sA[64 * SAS];           // feat bf16, 9216 B
  __shared__ u16 sB[64 * SAS];           // Wt bf16,  9216 B

  int tid       = threadIdx.x;
  int base_slot = blockIdx.x * 64;
  int r   = __builtin_amdgcn_readfirstlane(base_slot >> 12);  // uniform (CAP%64==0)
  int cnt = cursors[r];                                       // uniform -> s_load
  int bpos  = base_slot & (CAP - 1);
  int valid = cnt - bpos;                // block-uniform
  if (valid <= 0) return;                // whole block empty (uniform exit)
  if (valid > 64) valid = 64;

  if (tid < 64)
    srow[tid] = (tid < valid) ? idx_sorted[base_slot + tid] : -1;
  __syncthreads();

  // ---- stage features fp32->bf16: thread handles one 16B seg x 4 iters ----
  const v4f* f4 = reinterpret_cast<const v4f*>(features);
#pragma unroll
  for (int i = 0; i < 4; ++i) {
    int s   = i * 256 + tid;
    int rl  = s >> 4;                    // local row 0..63
    int seg = s & 15;                    // 4-float segment
    if (rl < valid) {
      v4f fv = f4[(size_t)srow[rl] * 16 + seg];
      u16x4 p = { f2bf(fv[0]), f2bf(fv[1]), f2bf(fv[2]), f2bf(fv[3]) };
      *reinterpret_cast<u16x4*>(&sA[rl * SAS + seg * 4]) = p;
    }
    // rows >= valid left as garbage: their MFMA outputs are never stored
  }

  // ---- stage Wt (8 KB, coalesced 8B chunks) ----
  const u16x4* w4 = reinterpret_cast<const u16x4*>(Wt + r * (FF * UU));
#pragma unroll
  for (int i = 0; i < 4; ++i) {
    int c    = i * 256 + tid;            // 1024 chunks of 4 bf16
    int u    = c >> 4;
    int fseg = c & 15;
    *reinterpret_cast<u16x4*>(&sB[u * SAS + fseg * 4]) = w4[c];
  }
  __syncthreads();

  int lane = tid & 63;
  int w    = __builtin_amdgcn_readfirstlane(tid >> 6);  // col-tile 0..3
  int m    = lane & 15;
  int quad = lane >> 4;

  // B fragments: col n = 16w+m, k-chunk h -> sB[n][32h + 8*quad ..+7]
  bf16x8 bfrag[2];
#pragma unroll
  for (int h = 0; h < 2; ++h)
    bfrag[h] = *reinterpret_cast<const bf16x8*>(
        &sB[(w * 16 + m) * SAS + h * 32 + quad * 8]);

  float bv = bias[w * 16 + m];           // col bias; C-layout col = lane&15
  f32x4 acc[4];
#pragma unroll
  for (int t = 0; t < 4; ++t) {
    acc[t] = (f32x4){bv, bv, bv, bv};
#pragma unroll
    for (int h = 0; h < 2; ++h) {
      bf16x8 afrag = *reinterpret_cast<const bf16x8*>(
          &sA[(t * 16 + m) * SAS + h * 32 + quad * 8]);
      acc[t] = __builtin_amdgcn_mfma_f32_16x16x32_bf16(afrag, bfrag[h], acc[t], 0, 0, 0);
    }
  }

  // ---- store: row = srow[16t + 4*quad + g], col = 16w + m ----
#pragma unroll
  for (int t = 0; t < 4; ++t) {
#pragma unroll
    for (int g = 0; g < 4; ++g) {
      int grow = srow[t * 16 + quad * 4 + g];  // LDS broadcast within quad
      if (grow >= 0)
        out[(size_t)grow * UU + w * 16 + m] = acc[t][g];  // 16-lane 64B runs
    }
  }
}

// ---------------------------------------------------------------------------
// Fallback (no workspace): fp32 on-the-fly W. Safety net only.
// ---------------------------------------------------------------------------
__global__ __launch_bounds__(256) void k_fallback(
    const float* __restrict__ features,
    const int*   __restrict__ rel,
    const float* __restrict__ kern,
    const float* __restrict__ lin,
    const float* __restrict__ bias,
    float*       __restrict__ out) {
  int tid = threadIdx.x;
  int row = blockIdx.x * 64 + (tid & 63);
  int q   = __builtin_amdgcn_readfirstlane(tid >> 6);
  int r   = rel[row];
  float cf[BB];
#pragma unroll
  for (int b = 0; b < BB; ++b) cf[b] = lin[r * BB + b];
  const v4f* fr = reinterpret_cast<const v4f*>(features + (size_t)row * FF);
  float acc[16];
#pragma unroll
  for (int j = 0; j < 16; ++j) acc[j] = bias[q * 16 + j];
#pragma unroll
  for (int ch = 0; ch < 4; ++ch) {
    v4f fv[4];
#pragma unroll
    for (int k = 0; k < 4; ++k) fv[k] = fr[ch * 4 + k];
#pragma unroll
    for (int k = 0; k < 4; ++k) {
#pragma unroll
      for (int c = 0; c < 4; ++c) {
        int f = ch * 16 + k * 4 + c;
        float fs = fv[k][c];
        float wf[16];
#pragma unroll
        for (int jj = 0; jj < 16; ++jj) wf[jj] = 0.f;
#pragma unroll
        for (int b = 0; b < BB; ++b) {
          const float* Vb = kern + b * (FF * UU) + f * UU + q * 16;
#pragma unroll
          for (int jj = 0; jj < 16; ++jj) wf[jj] += cf[b] * Vb[jj];
        }
#pragma unroll
        for (int jj = 0; jj < 16; ++jj) acc[jj] += fs * wf[jj];
      }
    }
  }
  v4f* o4 = reinterpret_cast<v4f*>(out + (size_t)row * UU + q * 16);
#pragma unroll
  for (int j4 = 0; j4 < 4; ++j4) {
    v4f v = {acc[4 * j4], acc[4 * j4 + 1], acc[4 * j4 + 2], acc[4 * j4 + 3]};
    o4[j4] = v;
  }
}

extern "C" void kernel_launch(void* const* d_in, const int* in_sizes, int n_in,
                              void* d_out, int out_size, void* d_ws, size_t ws_size,
                              hipStream_t stream) {
  const float* features  = (const float*)d_in[0];
  const int*   relations = (const int*)d_in[1];
  const float* kern      = (const float*)d_in[2];
  const float* lin       = (const float*)d_in[3];
  const float* bias      = (const float*)d_in[4];
  float* out = (float*)d_out;

  if (ws_size >= WS_NEED) {
    char* ws          = (char*)d_ws;
    int*  idx_sorted  = (int*)(ws + IDX_OFF);
    int*  cursors     = (int*)(ws + CUR_OFF);
    u16*  Wt          = (u16*)(ws + WT_OFF);
    (void)hipMemsetAsync(cursors, 0, RR * sizeof(int), stream);   // 100 B only
    k_prep<<<(RR * FF * UU) / 256 + NN / 256, 256, 0, stream>>>(
        kern, lin, relations, Wt, idx_sorted, cursors);
    k_main<<<NSLOT / 64, 256, 0, stream>>>(features, bias, Wt, idx_sorted, cursors, out);
  } else {
    k_fallback<<<NN / 64, 256, 0, stream>>>(features, relations, kern, lin, bias, out);
  }
}

// Round 8
// 83.825 us; speedup vs baseline: 1.2684x; 1.0405x over previous
//
#include <hip/hip_runtime.h>

// RelationalDense: out[n,:] = feat[n,:] @ W[rel[n]] + bias,  W = einsum('rb,bfo', lin, V)
// N=65536, F=64, U=64, R=25, B=8.
//
// R7 (87.2 us): bf16 MFMA, bucket-by-relation, 3 dispatches (memset+prep+main).
// Controllable span ~10 us of the 87 (rest = harness poison/restore wall).
// R8: kill the memset dispatch + all global atomics. Deterministic init-free
// bucketing: per-(source-block sb, relation r) subrange of 64 slots,
// rank from block-local LDS histogram; counts to bcnt[sb][r] written
// unconditionally (nothing needs pre-zeroing; poison never read).
// Per-cell count ~Binomial(256,1/25): mean 10.2, sigma 3.1 -> 64 is 17 sigma.
// k_main: block b -> (r=b>>8, sb=b&255); only ceil(valid/16) row-tiles run
// (usually 1 -> 2 MFMAs); W L2 re-staging 4x (52 MB L2, XCD-local, ~1.5 us
// overlapped) is the price for dropping a dispatch + atomics.

typedef float v4f __attribute__((ext_vector_type(4)));
typedef short bf16x8 __attribute__((ext_vector_type(8)));
typedef float f32x4 __attribute__((ext_vector_type(4)));
typedef unsigned short u16;
typedef u16 u16x4 __attribute__((ext_vector_type(4)));

#define NN 65536
#define FF 64
#define UU 64
#define RR 25
#define BB 8
#define SBN 256                  // scatter source blocks (256 rows each)
#define CAPB 64                  // slots per (sb, r) cell; 17 sigma above mean
#define NSLOT (RR * SBN * CAPB)  // 409600
#define SAS 72                   // LDS row stride in bf16 units (144 B, 16B-aligned)

// ws layout (nothing pre-initialized; validity always derived from bcnt):
//   [0, NSLOT*4)             idx_sorted (int)
//   [BCNT_OFF, +SBN*RR*4)    bcnt[sb][r]  (written unconditionally by k_prep)
//   [WT_OFF, +R*U*F*2)       Wt bf16, transposed [R][U][F]
#define IDX_OFF  0
#define BCNT_OFF (NSLOT * 4)                  // 1638400
#define WT_OFF   (BCNT_OFF + SBN * RR * 4)    // 1664000 (128-aligned)
#define WS_NEED  ((size_t)(WT_OFF + RR * FF * UU * 2))

__device__ __forceinline__ u16 f2bf(float x) {
  union { float f; unsigned u; } v; v.f = x;
  unsigned r = v.u + 0x7FFF + ((v.u >> 16) & 1);   // round-to-nearest-even
  return (u16)(r >> 16);
}

// ---------------------------------------------------------------------------
// K1: fused W^T precompute (blocks [0,400)) + init-free bucket scatter
//     (blocks [400,656)). No global atomics, no memset dependency.
// ---------------------------------------------------------------------------
__global__ __launch_bounds__(256) void k_prep(
    const float* __restrict__ kern,   // [B,F,U]
    const float* __restrict__ lin,    // [R,B]
    const int*   __restrict__ rel,    // [N]
    u16*         __restrict__ Wt,     // [R,U,F] bf16
    int*         __restrict__ idx_sorted,
    int*         __restrict__ bcnt) { // [SBN][RR]
  const int wblocks = (RR * FF * UU) / 256;  // 400
  int bid = blockIdx.x;
  if (bid < wblocks) {
    int idx = bid * 256 + threadIdx.x;
    int r = __builtin_amdgcn_readfirstlane(idx >> 12);
    int f = (idx >> 6) & 63;
    int u = idx & 63;
    float acc = 0.f;
#pragma unroll
    for (int b = 0; b < BB; ++b)
      acc += lin[r * BB + b] * kern[b * (FF * UU) + f * UU + u];  // coalesced in u
    Wt[r * (FF * UU) + u * FF + f] = f2bf(acc);  // transposed write (tiny, 200 KB)
  } else {
    // scatter: LDS histogram -> in-block rank -> deterministic (sb,r) cell
    int sb  = bid - wblocks;
    int tid = threadIdx.x;
    __shared__ int cnt[RR];
    if (tid < RR) cnt[tid] = 0;
    __syncthreads();
    int row  = sb * 256 + tid;
    int r    = rel[row];
    int rank = atomicAdd(&cnt[r], 1);          // LDS atomic, block-local
    __syncthreads();
    if (tid < RR) bcnt[sb * RR + tid] = cnt[tid];
    if (rank < CAPB)                           // 17-sigma guard
      idx_sorted[(r * SBN + sb) * CAPB + rank] = row;
  }
}

// ---------------------------------------------------------------------------
// K2: MFMA compute. Block b -> cell (r = b>>8, sb = b&255), up to 64 rows.
// 4 waves = 4 col-tiles; only ceil(valid/16) row-tiles execute (usually 1).
// Layouts (verified in R7): A: m=lane&15, k=quad*8+j ; B: n=lane&15 (col),
// same k ; C: col=lane&15, row=quad*4+reg. Bias seeds acc via C-layout.
// ---------------------------------------------------------------------------
__global__ __launch_bounds__(256, 2) void k_main(
    const float* __restrict__ features,  // [N,F] fp32
    const float* __restrict__ bias,      // [U]
    const u16*   __restrict__ Wt,        // [R,U,F] bf16
    const int*   __restrict__ idx_sorted,
    const int*   __restrict__ bcnt,      // [SBN][RR]
    float*       __restrict__ out) {     // [N,U]
  __shared__ int srow[64];
  __shared__ u16 sA[64 * SAS];           // feat bf16, 9216 B
  __shared__ u16 sB[64 * SAS];           // Wt bf16,  9216 B

  int tid = threadIdx.x;
  int b   = blockIdx.x;
  int r   = __builtin_amdgcn_readfirstlane(b >> 8);  // uniform
  int sb  = b & 255;
  int valid = bcnt[sb * RR + r];                     // uniform -> s_load
  if (valid <= 0) return;                            // empty cell (uniform exit)
  if (valid > CAPB) valid = CAPB;

  int base = (r * SBN + sb) * CAPB;
  if (tid < 64)
    srow[tid] = (tid < valid) ? idx_sorted[base + tid] : -1;
  __syncthreads();

  // ---- stage features fp32->bf16 for valid rows ----
  const v4f* f4 = reinterpret_cast<const v4f*>(features);
#pragma unroll
  for (int i = 0; i < 4; ++i) {
    int s   = i * 256 + tid;
    int rl  = s >> 4;                    // local row 0..63
    int seg = s & 15;                    // 4-float segment
    if (rl < valid) {
      v4f fv = f4[(size_t)srow[rl] * 16 + seg];
      u16x4 p = { f2bf(fv[0]), f2bf(fv[1]), f2bf(fv[2]), f2bf(fv[3]) };
      *reinterpret_cast<u16x4*>(&sA[rl * SAS + seg * 4]) = p;
    }
  }

  // ---- stage Wt (8 KB, coalesced; L2-resident, XCD-local by block order) ----
  const u16x4* w4 = reinterpret_cast<const u16x4*>(Wt + r * (FF * UU));
#pragma unroll
  for (int i = 0; i < 4; ++i) {
    int c    = i * 256 + tid;            // 1024 chunks of 4 bf16
    int u    = c >> 4;
    int fseg = c & 15;
    *reinterpret_cast<u16x4*>(&sB[u * SAS + fseg * 4]) = w4[c];
  }
  __syncthreads();

  int lane = tid & 63;
  int w    = __builtin_amdgcn_readfirstlane(tid >> 6);  // col-tile 0..3
  int m    = lane & 15;
  int quad = lane >> 4;

  // B fragments: col n = 16w+m, k-chunk h -> sB[n][32h + 8*quad ..+7]
  bf16x8 bfrag[2];
#pragma unroll
  for (int h = 0; h < 2; ++h)
    bfrag[h] = *reinterpret_cast<const bf16x8*>(
        &sB[(w * 16 + m) * SAS + h * 32 + quad * 8]);

  float bv = bias[w * 16 + m];           // col bias; C-layout col = lane&15
  int nt = (valid + 15) >> 4;            // row-tiles, uniform (1..4, usually 1)

  for (int t = 0; t < nt; ++t) {
    f32x4 acc = (f32x4){bv, bv, bv, bv};
#pragma unroll
    for (int h = 0; h < 2; ++h) {
      bf16x8 afrag = *reinterpret_cast<const bf16x8*>(
          &sA[(t * 16 + m) * SAS + h * 32 + quad * 8]);
      acc = __builtin_amdgcn_mfma_f32_16x16x32_bf16(afrag, bfrag[h], acc, 0, 0, 0);
    }
#pragma unroll
    for (int g = 0; g < 4; ++g) {
      int grow = srow[t * 16 + quad * 4 + g];  // LDS broadcast within quad
      if (grow >= 0)
        out[(size_t)grow * UU + w * 16 + m] = acc[g];  // 16-lane 64B runs
    }
  }
}

// ---------------------------------------------------------------------------
// Fallback (no workspace): fp32 on-the-fly W. Safety net only.
// ---------------------------------------------------------------------------
__global__ __launch_bounds__(256) void k_fallback(
    const float* __restrict__ features,
    const int*   __restrict__ rel,
    const float* __restrict__ kern,
    const float* __restrict__ lin,
    const float* __restrict__ bias,
    float*       __restrict__ out) {
  int tid = threadIdx.x;
  int row = blockIdx.x * 64 + (tid & 63);
  int q   = __builtin_amdgcn_readfirstlane(tid >> 6);
  int r   = rel[row];
  float cf[BB];
#pragma unroll
  for (int b = 0; b < BB; ++b) cf[b] = lin[r * BB + b];
  const v4f* fr = reinterpret_cast<const v4f*>(features + (size_t)row * FF);
  float acc[16];
#pragma unroll
  for (int j = 0; j < 16; ++j) acc[j] = bias[q * 16 + j];
#pragma unroll
  for (int ch = 0; ch < 4; ++ch) {
    v4f fv[4];
#pragma unroll
    for (int k = 0; k < 4; ++k) fv[k] = fr[ch * 4 + k];
#pragma unroll
    for (int k = 0; k < 4; ++k) {
#pragma unroll
      for (int c = 0; c < 4; ++c) {
        int f = ch * 16 + k * 4 + c;
        float fs = fv[k][c];
        float wf[16];
#pragma unroll
        for (int jj = 0; jj < 16; ++jj) wf[jj] = 0.f;
#pragma unroll
        for (int b = 0; b < BB; ++b) {
          const float* Vb = kern + b * (FF * UU) + f * UU + q * 16;
#pragma unroll
          for (int jj = 0; jj < 16; ++jj) wf[jj] += cf[b] * Vb[jj];
        }
#pragma unroll
        for (int jj = 0; jj < 16; ++jj) acc[jj] += fs * wf[jj];
      }
    }
  }
  v4f* o4 = reinterpret_cast<v4f*>(out + (size_t)row * UU + q * 16);
#pragma unroll
  for (int j4 = 0; j4 < 4; ++j4) {
    v4f v = {acc[4 * j4], acc[4 * j4 + 1], acc[4 * j4 + 2], acc[4 * j4 + 3]};
    o4[j4] = v;
  }
}

extern "C" void kernel_launch(void* const* d_in, const int* in_sizes, int n_in,
                              void* d_out, int out_size, void* d_ws, size_t ws_size,
                              hipStream_t stream) {
  const float* features  = (const float*)d_in[0];
  const int*   relations = (const int*)d_in[1];
  const float* kern      = (const float*)d_in[2];
  const float* lin       = (const float*)d_in[3];
  const float* bias      = (const float*)d_in[4];
  float* out = (float*)d_out;

  if (ws_size >= WS_NEED) {
    char* ws         = (char*)d_ws;
    int*  idx_sorted = (int*)(ws + IDX_OFF);
    int*  bcnt       = (int*)(ws + BCNT_OFF);
    u16*  Wt         = (u16*)(ws + WT_OFF);
    k_prep<<<(RR * FF * UU) / 256 + SBN, 256, 0, stream>>>(
        kern, lin, relations, Wt, idx_sorted, bcnt);
    k_main<<<RR * SBN, 256, 0, stream>>>(features, bias, Wt, idx_sorted, bcnt, out);
  } else {
    k_fallback<<<NN / 64, 256, 0, stream>>>(features, relations, kern, lin, bias, out);
  }
}